// Round 19
// baseline (190.401 us; speedup 1.0000x reference)
//
#include <hip/hip_runtime.h>

typedef __attribute__((ext_vector_type(8))) short short8;
typedef __attribute__((ext_vector_type(4))) float f32x4;
typedef __attribute__((ext_vector_type(4))) int i32x4;

#define HW 65536

__device__ __forceinline__ float bf2f(unsigned short u){
    union { unsigned int i; float f; } x; x.i = ((unsigned int)u) << 16; return x.f;
}
__device__ __forceinline__ unsigned short f2bf(float f){
    union { float f; unsigned int i; } x; x.f = f;
    unsigned int r = x.i + 0x7fffu + ((x.i >> 16) & 1u);
    return (unsigned short)(r >> 16);
}
__device__ __forceinline__ unsigned int pack2(float a, float b){
    return (unsigned int)f2bf(a) | ((unsigned int)f2bf(b) << 16);
}
__device__ __forceinline__ i32x4 addrelu4(i32x4 a, i32x4 b){
    i32x4 o;
#pragma unroll
    for (int k = 0; k < 4; ++k) {
        unsigned int ua = (unsigned int)a[k], ub = (unsigned int)b[k];
        float x0 = bf2f((unsigned short)(ua & 0xffff)) + bf2f((unsigned short)(ub & 0xffff));
        float x1 = bf2f((unsigned short)(ua >> 16))    + bf2f((unsigned short)(ub >> 16));
        o[k] = (int)(((unsigned int)f2bf(fmaxf(x0, 0.f))) |
                     ((unsigned int)f2bf(fmaxf(x1, 0.f)) << 16));
    }
    return o;
}

// ---------------------------------------------------------------------------
// Merged dual single-conv (dil=1, KK=1): blockIdx.z -> (which, batch).
// ---------------------------------------------------------------------------
template<int PRELU>
__global__ __launch_bounds__(256, 4) void sconv2_k(
    const unsigned short* __restrict__ inA, const unsigned short* __restrict__ wfA,
    const float* __restrict__ biasA, const float* __restrict__ alA, int coffA,
    const unsigned short* __restrict__ inB, const unsigned short* __restrict__ wfB,
    const float* __restrict__ biasB, const float* __restrict__ alB, int coffB,
    unsigned short* __restrict__ outb, int cpad)
{
    constexpr int CPIN = 32, SGR = 4, SGRP = 5, SPX = 66;
    constexpr int NSTGDW = 3 * SPX * SGRP * 4;
    constexpr int ODP = 20;
    constexpr int OUTOFF = NSTGDW;
    __shared__ __align__(16) unsigned int sm[NSTGDW + 64 * ODP];
    const int tid = threadIdx.x;
    const int lane = tid & 63, wv = tid >> 6;
    const int col = lane & 15, g = lane >> 4;
    const int bx = blockIdx.x;
    const int xcd = bx & 7, t = bx >> 3;
    const int y0 = xcd * 32 + (t & 31);
    const int x0 = ((t >> 5) & 3) * 64;
    const int which = blockIdx.z >> 1, b = blockIdx.z & 1;
    const unsigned short* in = which ? inB : inA;
    const unsigned short* wfrag = which ? wfB : wfA;
    const float* bias = which ? biasB : biasA;
    const float* alphap = which ? alB : alA;
    const int coff = which ? coffB : coffA;
    const unsigned short* inb = in + (size_t)b * HW * CPIN;

#pragma unroll
    for (int rr = 0; rr < 3; ++rr) {
        const int yy = y0 + rr - 1;
        for (int u = tid; u < SPX * SGR; u += 256) {
            const int slot = u & (SGR - 1), px = u / SGR;
            const int xx = x0 - 1 + px;
            i32x4 v = {0,0,0,0};
            if ((unsigned)yy < 256u && (unsigned)xx < 256u)
                v = *(const i32x4*)(inb + (size_t)(yy * 256 + xx) * CPIN + slot * 8);
            *(i32x4*)&sm[((rr * SPX + px) * SGRP + slot) * 4] = v;
        }
    }
    if (tid < 64) sm[OUTOFF + tid * ODP + 15] = 0;
    __syncthreads();

    const short8* wp = (const short8*)wfrag;
    f32x4 acc[2][2];
#pragma unroll
    for (int mt = 0; mt < 2; ++mt)
#pragma unroll
        for (int c = 0; c < 2; ++c) acc[mt][c] = (f32x4){0.f,0.f,0.f,0.f};
#pragma unroll
    for (int tap = 0; tap < 9; ++tap) {
        const int dy = tap / 3 - 1, dx = tap % 3 - 1;
        const int rl = dy + 1;
        short8 af[2];
#pragma unroll
        for (int mt = 0; mt < 2; ++mt)
            af[mt] = wp[(tap * 2 + mt) * 64 + lane];
        const int pl = 1 + wv * 16 + col + dx;
        const int c2 = tap & 1;
        short8 bf = *(const short8*)&sm[((rl * SPX + pl) * SGRP + g) * 4];
#pragma unroll
        for (int mt = 0; mt < 2; ++mt)
            acc[mt][c2] = __builtin_amdgcn_mfma_f32_16x16x32_bf16(af[mt], bf, acc[mt][c2], 0, 0, 0);
    }
    const float al = PRELU ? __ldg(alphap) : 0.f;
    const int px = wv * 16 + col;
#pragma unroll
    for (int mt = 0; mt < 2; ++mt) {
        const f32x4 a = acc[mt][0] + acc[mt][1];
#pragma unroll
        for (int e = 0; e < 2; ++e) {
            const int rb = mt * 16 + g * 4 + e * 2;
            if (rb < 30) {
                float v0 = a[e * 2]     + __ldg(bias + rb);
                float v1 = a[e * 2 + 1] + ((rb + 1 < 30) ? __ldg(bias + rb + 1) : 0.f);
                if (PRELU) { v0 = v0 >= 0.f ? v0 : al * v0; v1 = v1 >= 0.f ? v1 : al * v1; }
                if (rb + 1 >= 30) v1 = 0.f;
                sm[OUTOFF + px * ODP + (rb >> 1)] = pack2(v0, v1);
            }
        }
    }
    __syncthreads();
    {
        const int slot = tid & 3, opx = tid >> 2;
        i32x4 v = *(i32x4*)&sm[OUTOFF + opx * ODP + slot * 4];
        const size_t go = ((size_t)b * HW + (size_t)y0 * 256 + x0 + opx) * cpad + coff + slot * 8;
        *(i32x4*)(outb + go) = v;
    }
}

// ---------------------------------------------------------------------------
// Row-pair single conv (KK=2 in, 30 out rows, pad32 out) — blk2.
// ---------------------------------------------------------------------------
template<int PRELU>
__global__ __launch_bounds__(256, 6) void sconvp_k(
    const unsigned short* __restrict__ in,
    const unsigned short* __restrict__ wfrag,
    const float* __restrict__ bias,
    const float* __restrict__ alphap,
    unsigned short* __restrict__ outb)
{
    constexpr int KK = 2, CPIN = 64, CPAD = 32;
    constexpr int SGR = 8, SGRP = 9, SPX = 34, SROWS = 4;
    constexpr int CPP = 4, ODP = 20;
    constexpr int NSTGDW = SROWS * SPX * SGRP * 4;
    constexpr int OUTOFF = NSTGDW;
    __shared__ __align__(16) unsigned int sm[NSTGDW + 64 * ODP];

    const int tid = threadIdx.x;
    const int lane = tid & 63, wv = tid >> 6;
    const int col = lane & 15, g = lane >> 4;
    const int bx = blockIdx.x;
    const int xcd = bx & 7, t = bx >> 3;
    const int y0 = xcd * 32 + (t & 15) * 2;
    const int x0 = ((t >> 4) & 7) * 32;
    const int b = blockIdx.z;
    const unsigned short* inb = in + (size_t)b * HW * CPIN;

    for (int u = tid; u < SROWS * SPX * SGR; u += 256) {
        const int slot = u & (SGR - 1);
        const int px = (u / SGR) % SPX;
        const int row = u / (SGR * SPX);
        const int yy = y0 + row - 1, xx = x0 - 1 + px;
        i32x4 v = {0,0,0,0};
        if ((unsigned)yy < 256u && (unsigned)xx < 256u)
            v = *(const i32x4*)(inb + (size_t)(yy * 256 + xx) * CPIN + slot * 8);
        *(i32x4*)&sm[((row * SPX + px) * SGRP + slot) * 4] = v;
    }
    if (tid < 64) sm[OUTOFF + tid * ODP + 15] = 0;
    __syncthreads();

    const int r = wv >> 1, xh = wv & 1;
    const short8* wp = (const short8*)wfrag;
    f32x4 acc[2][2];
#pragma unroll
    for (int mt = 0; mt < 2; ++mt)
#pragma unroll
        for (int c = 0; c < 2; ++c) acc[mt][c] = (f32x4){0.f,0.f,0.f,0.f};
#pragma unroll
    for (int tap = 0; tap < 9; ++tap) {
        const int dy = tap / 3 - 1, dx = tap % 3 - 1;
        const int rl = r + dy + 1;
        short8 af[2][KK];
#pragma unroll
        for (int mt = 0; mt < 2; ++mt)
#pragma unroll
            for (int kk = 0; kk < KK; ++kk)
                af[mt][kk] = wp[((tap * 2 + mt) * KK + kk) * 64 + lane];
        const int pl = 1 + xh * 16 + col + dx;
#pragma unroll
        for (int kk = 0; kk < KK; ++kk) {
            short8 bf = *(const short8*)&sm[((rl * SPX + pl) * SGRP + kk * 4 + g) * 4];
#pragma unroll
            for (int mt = 0; mt < 2; ++mt)
                acc[mt][kk] = __builtin_amdgcn_mfma_f32_16x16x32_bf16(af[mt][kk], bf, acc[mt][kk], 0, 0, 0);
        }
    }
    const float al = PRELU ? __ldg(alphap) : 0.f;
    const int px = xh * 16 + col;
#pragma unroll
    for (int mt = 0; mt < 2; ++mt) {
        const f32x4 a = acc[mt][0] + acc[mt][1];
#pragma unroll
        for (int e = 0; e < 2; ++e) {
            const int rb = mt * 16 + g * 4 + e * 2;
            if (rb < 30) {
                float v0 = a[e * 2]     + __ldg(bias + rb);
                float v1 = a[e * 2 + 1] + ((rb + 1 < 30) ? __ldg(bias + rb + 1) : 0.f);
                if (PRELU) { v0 = v0 >= 0.f ? v0 : al * v0; v1 = v1 >= 0.f ? v1 : al * v1; }
                if (rb + 1 >= 30) v1 = 0.f;
                sm[OUTOFF + (r * 32 + px) * ODP + (rb >> 1)] = pack2(v0, v1);
            }
        }
    }
    __syncthreads();

    for (int u = tid; u < 64 * CPP; u += 256) {
        const int slot = u & (CPP - 1), pxr = u / CPP;
        const int rr = pxr >> 5, opx = pxr & 31;
        i32x4 v = *(i32x4*)&sm[OUTOFF + pxr * ODP + slot * 4];
        const size_t go = ((size_t)b * HW + (size_t)(y0 + rr) * 256 + x0 + opx) * CPAD + slot * 8;
        *(i32x4*)(outb + go) = v;
    }
}

// ---------------------------------------------------------------------------
// Trident Q: row-QUAD blocks. 32-px tile, 4 output rows, 10-row halo staged
// once (2.5 rows/out-row). 384 thr = 6 waves = (dil, x-half), NF=1, 4 rows,
// full MT, single chain. Out tile overlays stage. 3 barriers.
// ---------------------------------------------------------------------------
template<int KK, int MR>
__global__ __launch_bounds__(384, (KK == 2 ? 4 : 6)) void trident_q(
    const unsigned short* __restrict__ in,
    const unsigned short* __restrict__ wf0, const unsigned short* __restrict__ wf1,
    const unsigned short* __restrict__ wf2,
    const float* __restrict__ b0, const float* __restrict__ b1, const float* __restrict__ b2,
    unsigned short* __restrict__ outb)
{
    constexpr int CPIN = KK * 32, CPAD = KK * 32;
    constexpr int SGR = KK * 4, SGRP = SGR + 1, SPX = 38, SROWS = 10;
    constexpr int MT_ = (KK == 2) ? 2 : 1;
    constexpr int CPP = KK * 4, ODP = (CPP + 1) * 4;
    constexpr int NSTGDW = SROWS * SPX * SGRP * 4;
    __shared__ __align__(16) unsigned int sm[NSTGDW];

    const int tid = threadIdx.x;
    const int lane = tid & 63, wv = tid >> 6;     // wv in [0,6)
    const int col = lane & 15, g = lane >> 4;
    const int bx = blockIdx.x;
    const int xcd = bx & 7, t = bx >> 3;          // t in [0,64)
    const int y0 = xcd * 32 + (t & 7) * 4;        // quad base row
    const int x0 = ((t >> 3) & 7) * 32;
    const int b = blockIdx.z;
    const unsigned short* inb = in + (size_t)b * HW * CPIN;

    // ---- stage rows y0-3 .. y0+6, px x0-3 .. x0+35 (single phase) ----
    for (int u = tid; u < SROWS * SPX * SGR; u += 384) {
        const int slot = u & (SGR - 1);
        const int px = (u / SGR) % SPX;
        const int row = u / (SGR * SPX);
        const int yy = y0 + row - 3, xx = x0 - 3 + px;
        i32x4 v = {0,0,0,0};
        if ((unsigned)yy < 256u && (unsigned)xx < 256u)
            v = *(const i32x4*)(inb + (size_t)(yy * 256 + xx) * CPIN + slot * 8);
        *(i32x4*)&sm[((row * SPX + px) * SGRP + slot) * 4] = v;
    }
    __syncthreads();

    // ---- compute: wave = (dil, xh), NF=1, 4 rows, full MT ----
    const int dil = wv >> 1, d = dil + 1, xh = wv & 1;
    const unsigned short* wfx = (dil == 0) ? wf0 : ((dil == 1) ? wf1 : wf2);
    const float* bs = (dil == 0) ? b0 : ((dil == 1) ? b1 : b2);
    const short8* wp = (const short8*)wfx;

    f32x4 acc[4][MT_];
#pragma unroll
    for (int rr = 0; rr < 4; ++rr)
#pragma unroll
        for (int mt = 0; mt < MT_; ++mt) acc[rr][mt] = (f32x4){0.f,0.f,0.f,0.f};

#pragma unroll
    for (int tap = 0; tap < 9; ++tap) {
        const int dy = tap / 3 - 1, dx = tap % 3 - 1;
        short8 af[MT_][KK];
#pragma unroll
        for (int mt = 0; mt < MT_; ++mt)
#pragma unroll
            for (int kk = 0; kk < KK; ++kk)
                af[mt][kk] = wp[((tap * MT_ + mt) * KK + kk) * 64 + lane];
        const int pl = 3 + xh * 16 + col + dx * d;
#pragma unroll
        for (int rr = 0; rr < 4; ++rr) {
            const int rl = 3 + rr + dy * d;
#pragma unroll
            for (int kk = 0; kk < KK; ++kk) {
                short8 bf = *(const short8*)&sm[((rl * SPX + pl) * SGRP + kk * 4 + g) * 4];
#pragma unroll
                for (int mt = 0; mt < MT_; ++mt)
                    acc[rr][mt] = __builtin_amdgcn_mfma_f32_16x16x32_bf16(af[mt][kk], bf, acc[rr][mt], 0, 0, 0);
            }
        }
    }
    __syncthreads();   // stage reads done; overlay out tile [4][32][ODP]

    {
        const int px = xh * 16 + col;
#pragma unroll
        for (int rr = 0; rr < 4; ++rr) {
            const int base = (rr * 32 + px) * ODP;
#pragma unroll
            for (int mt = 0; mt < MT_; ++mt) {
#pragma unroll
                for (int e = 0; e < 2; ++e) {
                    const int rb = mt * 16 + g * 4 + e * 2;
                    if (rb < MR) {
                        float v0 = acc[rr][mt][e * 2] + __ldg(bs + rb);
                        float v1 = (rb + 1 < MR) ? acc[rr][mt][e * 2 + 1] + __ldg(bs + rb + 1) : 0.f;
                        sm[base + ((dil * MR + rb) >> 1)] = pack2(v0, v1);
                    }
                }
            }
        }
        constexpr int NPAD = CPP * 4 - 3 * MR / 2;   // pad dwords per px
        for (int u = tid; u < 128 * NPAD; u += 384) {
            const int pxr = u / NPAD, dwp = 3 * MR / 2 + u % NPAD;
            sm[pxr * ODP + dwp] = 0;
        }
    }
    __syncthreads();

    for (int u = tid; u < 128 * CPP; u += 384) {
        const int slot = u & (CPP - 1), pxr = u / CPP;
        const int rr = pxr >> 5, opx = pxr & 31;
        i32x4 v = *(i32x4*)&sm[pxr * ODP + slot * 4];
        const size_t go = ((size_t)b * HW + (size_t)(y0 + rr) * 256 + x0 + opx) * CPAD + slot * 8;
        *(i32x4*)(outb + go) = v;
    }
}

// ---------------------------------------------------------------------------
// AFLB2: KK=2 row-pair fused AFLB (round-16 version).
// ---------------------------------------------------------------------------
template<int RES>
__global__ __launch_bounds__(256, 5) void aflb2_k(
    const unsigned short* __restrict__ in,
    const unsigned short* __restrict__ awf, const float* __restrict__ ab,
    const unsigned short* __restrict__ fwf,
    const unsigned short* __restrict__ res,
    unsigned short* __restrict__ outb)
{
    constexpr int KK = 2, CPIN = 64, MTT = 4, CPAD = 64;
    constexpr int SROWS = 4, SPX = 34, SGR = 8, SGRP = 9;
    constexpr int CPP = 8, ODP = (CPP + 1) * 4;
    constexpr int NSTGDW = SROWS * SPX * SGRP * 4;
    constexpr int ATOFF = NSTGDW;
    __shared__ __align__(16) unsigned int sm[ATOFF + 2 * 32 * ODP];

    const int tid = threadIdx.x;
    const int lane = tid & 63, wv = tid >> 6;
    const int col = lane & 15, g = lane >> 4;
    const int bx = blockIdx.x;
    const int xcd = bx & 7, t = bx >> 3;
    const int y0 = xcd * 32 + (t & 15) * 2;
    const int x0 = ((t >> 4) & 7) * 32;
    const int b = blockIdx.z;
    const unsigned short* inb = in + (size_t)b * HW * CPIN;

    for (int u = tid; u < SROWS * SPX * SGR; u += 256) {
        const int slot = u & (SGR - 1);
        const int px = (u / SGR) % SPX;
        const int row = u / (SGR * SPX);
        const int yy = y0 + row - 1, xx = x0 - 1 + px;
        i32x4 v = {0,0,0,0};
        if ((unsigned)yy < 256u && (unsigned)xx < 256u)
            v = *(const i32x4*)(inb + (size_t)(yy * 256 + xx) * CPIN + slot * 8);
        *(i32x4*)&sm[((row * SPX + px) * SGRP + slot) * 4] = v;
    }
    __syncthreads();

    const short8* awp = (const short8*)awf;
    const short8* fwp = (const short8*)fwf;

    {
        const int r = wv >> 1, apx0 = (wv & 1) * 16;
        f32x4 aacc[2];
        aacc[0] = (f32x4){0.f,0.f,0.f,0.f}; aacc[1] = (f32x4){0.f,0.f,0.f,0.f};
#pragma unroll
        for (int tap = 0; tap < 9; ++tap) {
            const int dy = tap / 3 - 1, dx = tap % 3 - 1;
            const int rl = r + dy + 1;
            const int pl = 1 + apx0 + col + dx;
#pragma unroll
            for (int kk = 0; kk < KK; ++kk) {
                short8 afa = awp[(tap * KK + kk) * 64 + lane];
                short8 bf = *(const short8*)&sm[((rl * SPX + pl) * SGRP + kk * 4 + g) * 4];
                aacc[kk] = __builtin_amdgcn_mfma_f32_16x16x32_bf16(afa, bf, aacc[kk], 0, 0, 0);
            }
        }
        const f32x4 aa = aacc[0] + aacc[1];
        float v[4];
        float m = -1e30f;
#pragma unroll
        for (int rr = 0; rr < 4; ++rr) {
            const int row = g * 4 + rr;
            v[rr] = (row < 9) ? (aa[rr] + __ldg(ab + row)) : -1e30f;
            m = fmaxf(m, v[rr]);
        }
        m = fmaxf(m, __shfl_xor(m, 16));
        m = fmaxf(m, __shfl_xor(m, 32));
        float e[4]; float s = 0.f;
#pragma unroll
        for (int rr = 0; rr < 4; ++rr) { e[rr] = (g * 4 + rr < 9) ? __expf(v[rr] - m) : 0.f; s += e[rr]; }
        s += __shfl_xor(s, 16);
        s += __shfl_xor(s, 32);
        const float inv = 1.f / s;
        const int px = apx0 + col;
#pragma unroll
        for (int rr = 0; rr < 4; ++rr) {
            const int row = g * 4 + rr;
            if (row < 9) sm[ATOFF + (r * 32 + px) * 9 + row] = __float_as_uint(e[rr] * inv);
        }
    }
    __syncthreads();

    const int r = wv >> 1, mth = wv & 1;
    f32x4 acc[2][2];
#pragma unroll
    for (int mtl = 0; mtl < 2; ++mtl)
#pragma unroll
        for (int nf = 0; nf < 2; ++nf) acc[mtl][nf] = (f32x4){0.f,0.f,0.f,0.f};
#pragma unroll
    for (int tap = 0; tap < 9; ++tap) {
        const int dy = tap / 3 - 1, dx = tap % 3 - 1;
        const int rl = r + dy + 1;
        float av[2];
#pragma unroll
        for (int nf = 0; nf < 2; ++nf)
            av[nf] = __uint_as_float(sm[ATOFF + (r * 32 + nf * 16 + col) * 9 + tap]);
        short8 af[2][KK];
#pragma unroll
        for (int mtl = 0; mtl < 2; ++mtl)
#pragma unroll
            for (int kk = 0; kk < KK; ++kk)
                af[mtl][kk] = fwp[((tap * MTT + mth * 2 + mtl) * KK + kk) * 64 + lane];
#pragma unroll
        for (int nf = 0; nf < 2; ++nf) {
            const int pl = 1 + nf * 16 + col + dx;
            f32x4 p[2];
            p[0] = (f32x4){0.f,0.f,0.f,0.f}; p[1] = (f32x4){0.f,0.f,0.f,0.f};
#pragma unroll
            for (int kk = 0; kk < KK; ++kk) {
                short8 bf = *(const short8*)&sm[((rl * SPX + pl) * SGRP + kk * 4 + g) * 4];
#pragma unroll
                for (int mtl = 0; mtl < 2; ++mtl)
                    p[mtl] = __builtin_amdgcn_mfma_f32_16x16x32_bf16(af[mtl][kk], bf, p[mtl], 0, 0, 0);
            }
#pragma unroll
            for (int mtl = 0; mtl < 2; ++mtl)
#pragma unroll
                for (int rr = 0; rr < 4; ++rr)
                    acc[mtl][nf][rr] = fmaf(av[nf], p[mtl][rr], acc[mtl][nf][rr]);
        }
    }
    __syncthreads();

#pragma unroll
    for (int mtl = 0; mtl < 2; ++mtl) {
        const int mt = mth * 2 + mtl;
#pragma unroll
        for (int nf = 0; nf < 2; ++nf) {
            const int px = nf * 16 + col;
            const int base = ATOFF + (r * 32 + px) * ODP;
            const int rp = mt * 8 + g * 2;
            unsigned long long w =
                (unsigned long long)pack2(acc[mtl][nf][0], acc[mtl][nf][1]) |
                ((unsigned long long)pack2(acc[mtl][nf][2], acc[mtl][nf][3]) << 32);
            *(unsigned long long*)&sm[base + rp] = w;
        }
    }
    __syncthreads();

    for (int u = tid; u < 2 * 32 * CPP; u += 256) {
        const int slot = u & (CPP - 1), pxr = u / CPP;
        const int rr = pxr >> 5, opx = pxr & 31;
        i32x4 v = *(i32x4*)&sm[ATOFF + pxr * ODP + slot * 4];
        const size_t go = ((size_t)b * HW + (size_t)(y0 + rr) * 256 + x0 + opx) * CPAD + slot * 8;
        if (RES) v = addrelu4(v, *(const i32x4*)(res + go));
        *(i32x4*)(outb + go) = v;
    }
}

// ---------------------------------------------------------------------------
// Staged fused AFLB (KK=1, RPB=2 — 30ch path, round-11 version).
// ---------------------------------------------------------------------------
template<int KK, int RPB, int RES>
__global__ __launch_bounds__(256, 4) void aflb_p(
    const unsigned short* __restrict__ in,
    const unsigned short* __restrict__ awf, const float* __restrict__ ab,
    const unsigned short* __restrict__ fwf,
    const unsigned short* __restrict__ res,
    unsigned short* __restrict__ outb)
{
    constexpr int CPIN = KK * 32, MTT = 2 * KK, CPAD = 16 * MTT;
    constexpr int SROWS = RPB + 2, SPX = 66, SGR = KK * 4, SGRP = SGR + 1;
    constexpr int CPP = CPAD / 8, ODP = (CPP + 1) * 4;
    constexpr int NSTGDW = SROWS * SPX * SGRP * 4;
    constexpr int ATOFF = NSTGDW;
    constexpr int NATT = RPB * 64 * 9;
    constexpr int OUTOFF = ATOFF + NATT;
    __shared__ __align__(16) unsigned int sm[OUTOFF + RPB * 64 * ODP];

    const int tid = threadIdx.x;
    const int lane = tid & 63, wv = tid >> 6;
    const int col = lane & 15, g = lane >> 4;
    const int bx = blockIdx.x;
    const int xcd = bx & 7, t = bx >> 3;
    const int y0 = (RPB == 1) ? (xcd * 32 + (t & 31)) : (xcd * 32 + (t & 15) * 2);
    const int xseg = (RPB == 1) ? ((t >> 5) & 3) : ((t >> 4) & 3);
    const int x0 = xseg * 64;
    const int b = blockIdx.z;
    const unsigned short* inb = in + (size_t)b * HW * CPIN;

    for (int u = tid; u < SROWS * SPX * SGR; u += 256) {
        const int slot = u & (SGR - 1);
        const int px = (u / SGR) % SPX;
        const int row = u / (SGR * SPX);
        const int yy = y0 + row - 1, xx = x0 - 1 + px;
        i32x4 v = {0,0,0,0};
        if ((unsigned)yy < 256u && (unsigned)xx < 256u)
            v = *(const i32x4*)(inb + (size_t)(yy * 256 + xx) * CPIN + slot * 8);
        *(i32x4*)&sm[((row * SPX + px) * SGRP + slot) * 4] = v;
    }
    __syncthreads();

    const short8* awp = (const short8*)awf;
    const short8* fwp = (const short8*)fwf;

    constexpr int NF1 = (RPB == 1) ? 1 : 2;
    const int arow = (RPB == 1) ? 0 : (wv >> 1);
    const int apx0 = (RPB == 1) ? (wv * 16) : ((wv & 1) * 32);
    f32x4 aacc[NF1][2];
#pragma unroll
    for (int nf = 0; nf < NF1; ++nf)
#pragma unroll
        for (int c = 0; c < 2; ++c) aacc[nf][c] = (f32x4){0.f,0.f,0.f,0.f};
#pragma unroll
    for (int tap = 0; tap < 9; ++tap) {
        const int dy = tap / 3 - 1, dx = tap % 3 - 1;
        const int rl = arow + dy + 1;
        short8 afa[KK];
#pragma unroll
        for (int kk = 0; kk < KK; ++kk)
            afa[kk] = awp[(tap * KK + kk) * 64 + lane];
#pragma unroll
        for (int nf = 0; nf < NF1; ++nf) {
            const int pl = 1 + apx0 + nf * 16 + col + dx;
#pragma unroll
            for (int kk = 0; kk < KK; ++kk) {
                const int c2 = (KK == 2) ? kk : (tap & 1);
                short8 bf = *(const short8*)&sm[((rl * SPX + pl) * SGRP + kk * 4 + g) * 4];
                aacc[nf][c2] = __builtin_amdgcn_mfma_f32_16x16x32_bf16(afa[kk], bf, aacc[nf][c2], 0, 0, 0);
            }
        }
    }
#pragma unroll
    for (int nf = 0; nf < NF1; ++nf) {
        const f32x4 aa = aacc[nf][0] + aacc[nf][1];
        float v[4];
        float m = -1e30f;
#pragma unroll
        for (int r = 0; r < 4; ++r) {
            const int row = g * 4 + r;
            v[r] = (row < 9) ? (aa[r] + __ldg(ab + row)) : -1e30f;
            m = fmaxf(m, v[r]);
        }
        m = fmaxf(m, __shfl_xor(m, 16));
        m = fmaxf(m, __shfl_xor(m, 32));
        float e[4]; float s = 0.f;
#pragma unroll
        for (int r = 0; r < 4; ++r) { e[r] = (g * 4 + r < 9) ? __expf(v[r] - m) : 0.f; s += e[r]; }
        s += __shfl_xor(s, 16);
        s += __shfl_xor(s, 32);
        const float inv = 1.f / s;
        const int px = apx0 + nf * 16 + col;
#pragma unroll
        for (int r = 0; r < 4; ++r) {
            const int row = g * 4 + r;
            if (row < 9) sm[ATOFF + (arow * 64 + px) * 9 + row] = __float_as_uint(e[r] * inv);
        }
    }
    __syncthreads();

    const int prow = (RPB == 1) ? 0 : (wv >> 1);
    const int mth  = (RPB == 1) ? (wv >> 1) : 0;
    const int nfh  = wv & 1;
    f32x4 acc[2][2];
#pragma unroll
    for (int mtl = 0; mtl < 2; ++mtl)
#pragma unroll
        for (int nf = 0; nf < 2; ++nf) acc[mtl][nf] = (f32x4){0.f,0.f,0.f,0.f};
#pragma unroll
    for (int tap = 0; tap < 9; ++tap) {
        const int dy = tap / 3 - 1, dx = tap % 3 - 1;
        const int rl = prow + dy + 1;
        float av[2];
#pragma unroll
        for (int nf = 0; nf < 2; ++nf)
            av[nf] = __uint_as_float(sm[ATOFF + (prow * 64 + nfh * 32 + nf * 16 + col) * 9 + tap]);
        short8 af[2][KK];
#pragma unroll
        for (int mtl = 0; mtl < 2; ++mtl)
#pragma unroll
            for (int kk = 0; kk < KK; ++kk)
                af[mtl][kk] = fwp[((tap * MTT + (RPB == 1 ? mth * 2 + mtl : mtl)) * KK + kk) * 64 + lane];
#pragma unroll
        for (int nf = 0; nf < 2; ++nf) {
            const int pl = 1 + nfh * 32 + nf * 16 + col + dx;
            f32x4 p[2];
            p[0] = (f32x4){0.f,0.f,0.f,0.f}; p[1] = (f32x4){0.f,0.f,0.f,0.f};
#pragma unroll
            for (int kk = 0; kk < KK; ++kk) {
                short8 bf = *(const short8*)&sm[((rl * SPX + pl) * SGRP + kk * 4 + g) * 4];
#pragma unroll
                for (int mtl = 0; mtl < 2; ++mtl)
                    p[mtl] = __builtin_amdgcn_mfma_f32_16x16x32_bf16(af[mtl][kk], bf, p[mtl], 0, 0, 0);
            }
#pragma unroll
            for (int mtl = 0; mtl < 2; ++mtl)
#pragma unroll
                for (int r = 0; r < 4; ++r)
                    acc[mtl][nf][r] = fmaf(av[nf], p[mtl][r], acc[mtl][nf][r]);
        }
    }
    __syncthreads();

#pragma unroll
    for (int mtl = 0; mtl < 2; ++mtl) {
        const int mt = (RPB == 1) ? (mth * 2 + mtl) : mtl;
#pragma unroll
        for (int nf = 0; nf < 2; ++nf) {
            const int px = nfh * 32 + nf * 16 + col;
            const int base = OUTOFF + ((RPB == 2 ? prow * 64 : 0) + px) * ODP;
            const int rp = mt * 8 + g * 2;
            unsigned long long w =
                (unsigned long long)pack2(acc[mtl][nf][0], acc[mtl][nf][1]) |
                ((unsigned long long)pack2(acc[mtl][nf][2], acc[mtl][nf][3]) << 32);
            *(unsigned long long*)&sm[base + rp] = w;
        }
    }
    __syncthreads();

    constexpr int NOUT = RPB * 64 * CPP;
    for (int u = tid; u < NOUT; u += 256) {
        const int slot = u & (CPP - 1);
        const int px = (u / CPP) & 63;
        const int r = (RPB == 2) ? (u / (CPP * 64)) : 0;
        i32x4 v = *(i32x4*)&sm[OUTOFF + ((r * 64 + px) * ODP) + slot * 4];
        const size_t go = ((size_t)b * HW + (size_t)(y0 + r) * 256 + x0 + px) * CPAD + slot * 8;
        if (RES) v = addrelu4(v, *(const i32x4*)(res + go));
        *(i32x4*)(outb + go) = v;
    }
}

// ---------------------------------------------------------------------------
// Final conv 30->4 + ms_up, f32 NCHW output.
// ---------------------------------------------------------------------------
__global__ __launch_bounds__(256, 4) void final_k(
    const unsigned short* __restrict__ in,
    const unsigned short* __restrict__ wfrag,
    const float* __restrict__ bias,
    const float* __restrict__ msup, float* __restrict__ outf)
{
    constexpr int CPIN = 32, NF = 2;
    const int lane = threadIdx.x & 63, wv = threadIdx.x >> 6;
    const int col = lane & 15, g = lane >> 4;
    const int bx = blockIdx.x;
    const int xcd = bx & 7, t = bx >> 3;
    const int y = xcd * 32 + (t & 31);
    const int xh = t >> 5;
    const int b = blockIdx.z;
    const int x0 = xh * 128 + wv * 32;

    const unsigned short* inb = in + (size_t)b * HW * CPIN;
    const short8 kz = {0,0,0,0,0,0,0,0};
    const short8* wp = (const short8*)wfrag;

    f32x4 acc[NF];
#pragma unroll
    for (int nf = 0; nf < NF; ++nf) acc[nf] = (f32x4){0.f,0.f,0.f,0.f};
#pragma unroll
    for (int tap = 0; tap < 9; ++tap) {
        const int dy = tap / 3 - 1, dx = tap % 3 - 1;
        const int yy = y + dy;
        const bool yok = (unsigned)yy < 256u;
        const short8 af = wp[tap * 64 + lane];
#pragma unroll
        for (int nf = 0; nf < NF; ++nf) {
            const int xx = x0 + nf * 16 + col + dx;
            const bool ok = yok && ((unsigned)xx < 256u);
            const int pix = ok ? (yy * 256 + xx) : 0;
            short8 bf = *(const short8*)(inb + (size_t)pix * CPIN + g * 8);
            if (!ok) bf = kz;
            acc[nf] = __builtin_amdgcn_mfma_f32_16x16x32_bf16(af, bf, acc[nf], 0, 0, 0);
        }
    }
#pragma unroll
    for (int nf = 0; nf < NF; ++nf) {
        const int pix = y * 256 + x0 + nf * 16 + col;
        if (g == 0) {
#pragma unroll
            for (int r = 0; r < 4; ++r) {
                const size_t oi = ((size_t)b * 4 + r) * HW + pix;
                outf[oi] = acc[nf][r] + __ldg(bias + r) + msup[oi];
            }
        }
    }
}

// ---------------------------------------------------------------------------
// Weight prep (parallel, shift-based indexing).
// ---------------------------------------------------------------------------
struct PrepDesc { const float* src; int cout, cin, kksh, mtsh, flags, dstoff, n; };
struct PrepArgs { PrepDesc d[18]; };

__global__ __launch_bounds__(256) void prep_k(PrepArgs pa, unsigned short* __restrict__ wb)
{
    const PrepDesc d = pa.d[blockIdx.y];
    const int e = blockIdx.x * 256 + threadIdx.x;
    if (e >= d.n) return;
    const int j = e & 7;
    const int lane = (e >> 3) & 63;
    const int i512 = e >> 9;
    const int kk = i512 & ((1 << d.kksh) - 1);
    const int mt = (i512 >> d.kksh) & ((1 << d.mtsh) - 1);
    const int tap = i512 >> (d.kksh + d.mtsh);
    const int rpos = mt * 16 + (lane & 15);
    const int kpos = kk * 32 + (lane >> 4) * 8 + j;
    int o = rpos, ic = kpos;
    bool ok = true;
    if (d.flags & 2) {
        if (rpos < 30) o = rpos;
        else if (rpos >= 32 && rpos < 62) o = rpos - 2;
        else ok = false;
    }
    if (d.flags & 1) {
        if (kpos < 30) ic = kpos;
        else if (kpos >= 32 && kpos < 62) ic = kpos - 2;
        else ok = false;
    }
    float v = 0.f;
    if (ok && o < d.cout && ic < d.cin) v = d.src[(o * d.cin + ic) * 9 + tap];
    wb[d.dstoff + e] = f2bf(v);
}

// ---------------------------------------------------------------------------
// up-conv (ms_org 4->64 @64x64, f32 NCHW) — small, VALU direct conv.
// ---------------------------------------------------------------------------
template<int CIN, int COUT, int OCB, int H, int W>
__launch_bounds__(256)
__global__ void upconv_k(const float* __restrict__ in, const float* __restrict__ wgt,
                         const float* __restrict__ bias, float* __restrict__ out)
{
    constexpr int HWp = H * W;
    constexpr int NOCB = COUT / OCB;
    const int tx = threadIdx.x;
    const int lx = tx & 63, ly = tx >> 6;
    const int gx = blockIdx.x * 64 + lx;
    const int gy = blockIdx.y * 4 + ly;
    const int b = blockIdx.z / NOCB;
    const int ocb = blockIdx.z % NOCB;
    const int pixp = gy * W + gx;
    const float* inb = in + (size_t)b * CIN * HWp;

    int off[9]; float mul[9];
#pragma unroll
    for (int dy = 0; dy < 3; ++dy)
#pragma unroll
        for (int dx = 0; dx < 3; ++dx) {
            int p = dy * 3 + dx;
            int yy = gy + dy - 1, xx = gx + dx - 1;
            bool okp = ((unsigned)yy < (unsigned)H) && ((unsigned)xx < (unsigned)W);
            off[p] = okp ? (yy * W + xx) : 0;
            mul[p] = okp ? 1.f : 0.f;
        }
    float acc[OCB];
#pragma unroll
    for (int o = 0; o < OCB; ++o) acc[o] = 0.f;
    const float* wbase = wgt + (size_t)(ocb * OCB) * CIN * 9;
#pragma unroll
    for (int ic = 0; ic < CIN; ++ic) {
        const float* ip = inb + (size_t)ic * HWp;
        float tv[9];
#pragma unroll
        for (int p = 0; p < 9; ++p) tv[p] = __ldg(ip + off[p]) * mul[p];
#pragma unroll
        for (int o = 0; o < OCB; ++o) {
            const float* wq = wbase + (size_t)(o * CIN + ic) * 9;
#pragma unroll
            for (int p = 0; p < 9; ++p) acc[o] = fmaf(tv[p], wq[p], acc[o]);
        }
    }
#pragma unroll
    for (int o = 0; o < OCB; ++o)
        out[((size_t)b * COUT + ocb * OCB + o) * HWp + pixp] = acc[o] + __ldg(bias + ocb * OCB + o);
}

// ---------------------------------------------------------------------------
// Build data1 (prelu(pixshuf(t_up))||pan) and ms_up as NHWC bf16 pad32.
// ---------------------------------------------------------------------------
__global__ __launch_bounds__(256) void build_inputs(
    const float* __restrict__ tup, const float* __restrict__ pan,
    const float* __restrict__ aup, const float* __restrict__ msup,
    unsigned short* __restrict__ data1, unsigned short* __restrict__ msb)
{
    const int i = blockIdx.x * 256 + threadIdx.x;
    const int b = i >> 16, pixp = i & 65535;
    const int y = pixp >> 8, x = pixp & 255;
    unsigned short o[32];
#pragma unroll
    for (int c = 0; c < 32; ++c) o[c] = 0;
    unsigned short* dst;
    if (blockIdx.y == 0) {
        const float a = __ldg(aup);
#pragma unroll
        for (int c = 0; c < 4; ++c) {
            const int ch = c * 16 + (y & 3) * 4 + (x & 3);
            float v = tup[(((size_t)b * 64 + ch) << 12) + ((y >> 2) << 6) + (x >> 2)];
            v = (v >= 0.f) ? v : a * v;
            o[c] = f2bf(v);
        }
        o[4] = f2bf(pan[((size_t)b << 16) + pixp]);
        dst = data1;
    } else {
#pragma unroll
        for (int c = 0; c < 4; ++c)
            o[c] = f2bf(msup[(((size_t)b * 4 + c) << 16) + pixp]);
        dst = msb;
    }
    short8* dp = (short8*)(dst + (size_t)i * 32);
#pragma unroll
    for (int q = 0; q < 4; ++q) {
        short8 s;
#pragma unroll
        for (int r = 0; r < 8; ++r) s[r] = (short)o[q * 8 + r];
        dp[q] = s;
    }
}

// ---------------------------------------------------------------------------
extern "C" void kernel_launch(void* const* d_in, const int* in_sizes, int n_in,
                              void* d_out, int out_size, void* d_ws, size_t ws_size,
                              hipStream_t stream) {
    const float* ms_up  = (const float*)d_in[0];
    const float* ms_org = (const float*)d_in[1];
    const float* pan    = (const float*)d_in[2];
    const float* w_up4  = (const float*)d_in[3];
    const float* b_up4  = (const float*)d_in[4];
    const float* a_up4  = (const float*)d_in[5];
    const float* w_blk53= (const float*)d_in[6];
    const float* b_blk53= (const float*)d_in[7];
    const float* a_blk53= (const float*)d_in[8];
    const float* w_blk43= (const float*)d_in[9];
    const float* b_blk43= (const float*)d_in[10];
    const float* a_blk43= (const float*)d_in[11];
    const float* w1a=(const float*)d_in[12]; const float* b1a=(const float*)d_in[13];
    const float* w1b=(const float*)d_in[14]; const float* b1b=(const float*)d_in[15];
    const float* w1c=(const float*)d_in[16]; const float* b1c=(const float*)d_in[17];
    const float* aw1=(const float*)d_in[18]; const float* ab1=(const float*)d_in[19];
    const float* fw1=(const float*)d_in[20];
    const float* aw2=(const float*)d_in[21]; const float* ab2=(const float*)d_in[22];
    const float* fw2=(const float*)d_in[23];
    const float* w_blk2=(const float*)d_in[24]; const float* b_blk2=(const float*)d_in[25]; const float* a_blk2=(const float*)d_in[26];
    const float* w2a=(const float*)d_in[27]; const float* b2a=(const float*)d_in[28];
    const float* w2b=(const float*)d_in[29]; const float* b2b=(const float*)d_in[30];
    const float* w2c=(const float*)d_in[31]; const float* b2c=(const float*)d_in[32];
    const float* aw3=(const float*)d_in[33]; const float* ab3=(const float*)d_in[34];
    const float* fw3=(const float*)d_in[35];
    const float* aw4=(const float*)d_in[36]; const float* ab4=(const float*)d_in[37];
    const float* fw4=(const float*)d_in[38];
    const float* w_c6=(const float*)d_in[39]; const float* b_c6=(const float*)d_in[40];

    float* out = (float*)d_out;
    char* ws = (char*)d_ws;

    const size_t BIG = (size_t)2 * HW * 64 * 2;   // 16.78 MB (NHWC pad64 bf16)
    const size_t HALF = BIG / 2;
    unsigned short* bufA = (unsigned short*)(ws);
    unsigned short* bufB = (unsigned short*)(ws + BIG);
    unsigned short* bufC = (unsigned short*)(ws + 2 * BIG);
    unsigned short* data1 = bufC;
    float*          t_up  = (float*)(ws + 2 * BIG + HALF);
    unsigned short* msb   = bufB;
    unsigned short* bufD = bufC;
    unsigned short* bufE = bufB;
    unsigned short* bufF = bufA;
    unsigned short* wb = (unsigned short*)(ws + 3 * BIG);

    if (ws_size < 3 * BIG + 1000000) return;

    PrepArgs pa;
    int off = 0, li = 0;
    auto add = [&](const float* s, int cout, int cin, int mtsh, int kksh, int flags) {
        const int n = 9 << (mtsh + kksh + 9);
        pa.d[li].src = s; pa.d[li].cout = cout; pa.d[li].cin = cin;
        pa.d[li].kksh = kksh; pa.d[li].mtsh = mtsh; pa.d[li].flags = flags;
        pa.d[li].dstoff = off; pa.d[li].n = n;
        int ret = off; off += n; ++li; return ret;
    };
    const int o_blk43 = add(w_blk43, 30, 4, 1, 0, 0);
    const int o_blk53 = add(w_blk53, 30, 5, 1, 0, 0);
    const int o_w1a   = add(w1a, 20, 60, 1, 1, 1);
    const int o_w1b   = add(w1b, 20, 60, 1, 1, 1);
    const int o_w1c   = add(w1c, 20, 60, 1, 1, 1);
    const int o_aw1   = add(aw1,  9, 60, 0, 1, 0);
    const int o_fw1   = add(fw1, 60, 60, 2, 1, 0);
    const int o_aw2   = add(aw2,  9, 60, 0, 1, 0);
    const int o_fw2   = add(fw2, 60, 60, 2, 1, 2);
    const int o_blk2  = add(w_blk2, 30, 60, 1, 1, 1);
    const int o_w2a   = add(w2a, 10, 30, 0, 0, 0);
    const int o_w2b   = add(w2b, 10, 30, 0, 0, 0);
    const int o_w2c   = add(w2c, 10, 30, 0, 0, 0);
    const int o_aw3   = add(aw3,  9, 30, 0, 0, 0);
    const int o_fw3   = add(fw3, 30, 30, 1, 0, 0);
    const int o_aw4   = add(aw4,  9, 30, 0, 0, 0);
    const int o_fw4   = add(fw4, 30, 30, 1, 0, 0);
    const int o_c6    = add(w_c6,  4, 30, 0, 0, 0);

    prep_k<<<dim3(144, 18), 256, 0, stream>>>(pa, wb);

    upconv_k<4, 64, 16, 64, 64><<<dim3(1, 16, 8), 256, 0, stream>>>(ms_org, w_up4, b_up4, t_up);
    build_inputs<<<dim3(512, 2), 256, 0, stream>>>(t_up, pan, a_up4, ms_up, data1, msb);

    const dim3 B256(256), B384(384);
    const dim3 G2(1024, 1, 4);   // merged dual sconv
    const dim3 GP(1024, 1, 2);   // row-pair blocks
    const dim3 GQ(512, 1, 2);    // row-quad trident blocks
    const dim3 GH(512, 1, 2);    // RPB=2 staged / final

    // out1 (bufA, pad64, split-60): blk43 -> rows 0..29, blk53 -> rows 32..61
    sconv2_k<1><<<G2,B256,0,stream>>>(msb, wb+o_blk43, b_blk43, a_blk43, 0,
                                      data1, wb+o_blk53, b_blk53, a_blk53, 32,
                                      bufA, 64);

    // ---- rmrs1 (60 ch) ----
    trident_q<2,20><<<GQ,B384,0,stream>>>(bufA, wb+o_w1a, wb+o_w1b, wb+o_w1c, b1a, b1b, b1c, bufB);
    aflb2_k<0><<<GP,B256,0,stream>>>(bufB, wb+o_aw1, ab1, wb+o_fw1, nullptr, bufC);
    aflb2_k<1><<<GP,B256,0,stream>>>(bufC, wb+o_aw2, ab2, wb+o_fw2, bufA,   bufB);

    // blk2: out2 -> 30ch (bufD pad32), row-pair staged
    sconvp_k<1><<<GP,B256,0,stream>>>(bufB, wb+o_blk2, b_blk2, a_blk2, bufD);

    // ---- rmrs2 (30 ch) ----
    trident_q<1,10><<<GQ,B384,0,stream>>>(bufD, wb+o_w2a, wb+o_w2b, wb+o_w2c, b2a, b2b, b2c, bufE);
    aflb_p<1,2,0><<<GH,B256,0,stream>>>(bufE, wb+o_aw3, ab3, wb+o_fw3, nullptr, bufF);
    aflb_p<1,2,1><<<GH,B256,0,stream>>>(bufF, wb+o_aw4, ab4, wb+o_fw4, bufD,   bufE);

    // final: conv 30->4 + ms_up (f32 NCHW out)
    final_k<<<GH,B256,0,stream>>>(bufE, wb+o_c6, b_c6, ms_up, out);
}

// Round 20
// 188.444 us; speedup vs baseline: 1.0104x; 1.0104x over previous
//
#include <hip/hip_runtime.h>

typedef __attribute__((ext_vector_type(8))) short short8;
typedef __attribute__((ext_vector_type(4))) float f32x4;
typedef __attribute__((ext_vector_type(4))) int i32x4;

#define HW 65536

__device__ __forceinline__ float bf2f(unsigned short u){
    union { unsigned int i; float f; } x; x.i = ((unsigned int)u) << 16; return x.f;
}
__device__ __forceinline__ unsigned short f2bf(float f){
    union { float f; unsigned int i; } x; x.f = f;
    unsigned int r = x.i + 0x7fffu + ((x.i >> 16) & 1u);
    return (unsigned short)(r >> 16);
}
__device__ __forceinline__ unsigned int pack2(float a, float b){
    return (unsigned int)f2bf(a) | ((unsigned int)f2bf(b) << 16);
}
__device__ __forceinline__ i32x4 addrelu4(i32x4 a, i32x4 b){
    i32x4 o;
#pragma unroll
    for (int k = 0; k < 4; ++k) {
        unsigned int ua = (unsigned int)a[k], ub = (unsigned int)b[k];
        float x0 = bf2f((unsigned short)(ua & 0xffff)) + bf2f((unsigned short)(ub & 0xffff));
        float x1 = bf2f((unsigned short)(ua >> 16))    + bf2f((unsigned short)(ub >> 16));
        o[k] = (int)(((unsigned int)f2bf(fmaxf(x0, 0.f))) |
                     ((unsigned int)f2bf(fmaxf(x1, 0.f)) << 16));
    }
    return o;
}

// ---------------------------------------------------------------------------
// Merged dual single-conv (dil=1, KK=1): blockIdx.z -> (which, batch).
// ---------------------------------------------------------------------------
template<int PRELU>
__global__ __launch_bounds__(256, 4) void sconv2_k(
    const unsigned short* __restrict__ inA, const unsigned short* __restrict__ wfA,
    const float* __restrict__ biasA, const float* __restrict__ alA, int coffA,
    const unsigned short* __restrict__ inB, const unsigned short* __restrict__ wfB,
    const float* __restrict__ biasB, const float* __restrict__ alB, int coffB,
    unsigned short* __restrict__ outb, int cpad)
{
    constexpr int CPIN = 32, SGR = 4, SGRP = 5, SPX = 66;
    constexpr int NSTGDW = 3 * SPX * SGRP * 4;
    constexpr int ODP = 20;
    constexpr int OUTOFF = NSTGDW;
    __shared__ __align__(16) unsigned int sm[NSTGDW + 64 * ODP];
    const int tid = threadIdx.x;
    const int lane = tid & 63, wv = tid >> 6;
    const int col = lane & 15, g = lane >> 4;
    const int bx = blockIdx.x;
    const int xcd = bx & 7, t = bx >> 3;
    const int y0 = xcd * 32 + (t & 31);
    const int x0 = ((t >> 5) & 3) * 64;
    const int which = blockIdx.z >> 1, b = blockIdx.z & 1;
    const unsigned short* in = which ? inB : inA;
    const unsigned short* wfrag = which ? wfB : wfA;
    const float* bias = which ? biasB : biasA;
    const float* alphap = which ? alB : alA;
    const int coff = which ? coffB : coffA;
    const unsigned short* inb = in + (size_t)b * HW * CPIN;

#pragma unroll
    for (int rr = 0; rr < 3; ++rr) {
        const int yy = y0 + rr - 1;
        for (int u = tid; u < SPX * SGR; u += 256) {
            const int slot = u & (SGR - 1), px = u / SGR;
            const int xx = x0 - 1 + px;
            i32x4 v = {0,0,0,0};
            if ((unsigned)yy < 256u && (unsigned)xx < 256u)
                v = *(const i32x4*)(inb + (size_t)(yy * 256 + xx) * CPIN + slot * 8);
            *(i32x4*)&sm[((rr * SPX + px) * SGRP + slot) * 4] = v;
        }
    }
    if (tid < 64) sm[OUTOFF + tid * ODP + 15] = 0;
    __syncthreads();

    const short8* wp = (const short8*)wfrag;
    f32x4 acc[2][2];
#pragma unroll
    for (int mt = 0; mt < 2; ++mt)
#pragma unroll
        for (int c = 0; c < 2; ++c) acc[mt][c] = (f32x4){0.f,0.f,0.f,0.f};
#pragma unroll
    for (int tap = 0; tap < 9; ++tap) {
        const int dy = tap / 3 - 1, dx = tap % 3 - 1;
        const int rl = dy + 1;
        short8 af[2];
#pragma unroll
        for (int mt = 0; mt < 2; ++mt)
            af[mt] = wp[(tap * 2 + mt) * 64 + lane];
        const int pl = 1 + wv * 16 + col + dx;
        const int c2 = tap & 1;
        short8 bf = *(const short8*)&sm[((rl * SPX + pl) * SGRP + g) * 4];
#pragma unroll
        for (int mt = 0; mt < 2; ++mt)
            acc[mt][c2] = __builtin_amdgcn_mfma_f32_16x16x32_bf16(af[mt], bf, acc[mt][c2], 0, 0, 0);
    }
    const float al = PRELU ? __ldg(alphap) : 0.f;
    const int px = wv * 16 + col;
#pragma unroll
    for (int mt = 0; mt < 2; ++mt) {
        const f32x4 a = acc[mt][0] + acc[mt][1];
#pragma unroll
        for (int e = 0; e < 2; ++e) {
            const int rb = mt * 16 + g * 4 + e * 2;
            if (rb < 30) {
                float v0 = a[e * 2]     + __ldg(bias + rb);
                float v1 = a[e * 2 + 1] + ((rb + 1 < 30) ? __ldg(bias + rb + 1) : 0.f);
                if (PRELU) { v0 = v0 >= 0.f ? v0 : al * v0; v1 = v1 >= 0.f ? v1 : al * v1; }
                if (rb + 1 >= 30) v1 = 0.f;
                sm[OUTOFF + px * ODP + (rb >> 1)] = pack2(v0, v1);
            }
        }
    }
    __syncthreads();
    {
        const int slot = tid & 3, opx = tid >> 2;
        i32x4 v = *(i32x4*)&sm[OUTOFF + opx * ODP + slot * 4];
        const size_t go = ((size_t)b * HW + (size_t)y0 * 256 + x0 + opx) * cpad + coff + slot * 8;
        *(i32x4*)(outb + go) = v;
    }
}

// ---------------------------------------------------------------------------
// Row-pair single conv (KK=2 in, 30 out rows, pad32 out) — blk2.
// 32-px tile, 2 output rows, 4-row halo staged once (2 rows/out-row).
// 4 waves = (row, x-half), MT=2, dual-chain. PRELU epilogue.
// ---------------------------------------------------------------------------
template<int PRELU>
__global__ __launch_bounds__(256, 6) void sconvp_k(
    const unsigned short* __restrict__ in,
    const unsigned short* __restrict__ wfrag,
    const float* __restrict__ bias,
    const float* __restrict__ alphap,
    unsigned short* __restrict__ outb)
{
    constexpr int KK = 2, CPIN = 64, CPAD = 32;
    constexpr int SGR = 8, SGRP = 9, SPX = 34, SROWS = 4;
    constexpr int CPP = 4, ODP = 20;
    constexpr int NSTGDW = SROWS * SPX * SGRP * 4;
    constexpr int OUTOFF = NSTGDW;
    __shared__ __align__(16) unsigned int sm[NSTGDW + 64 * ODP];

    const int tid = threadIdx.x;
    const int lane = tid & 63, wv = tid >> 6;
    const int col = lane & 15, g = lane >> 4;
    const int bx = blockIdx.x;
    const int xcd = bx & 7, t = bx >> 3;
    const int y0 = xcd * 32 + (t & 15) * 2;
    const int x0 = ((t >> 4) & 7) * 32;
    const int b = blockIdx.z;
    const unsigned short* inb = in + (size_t)b * HW * CPIN;

    for (int u = tid; u < SROWS * SPX * SGR; u += 256) {
        const int slot = u & (SGR - 1);
        const int px = (u / SGR) % SPX;
        const int row = u / (SGR * SPX);
        const int yy = y0 + row - 1, xx = x0 - 1 + px;
        i32x4 v = {0,0,0,0};
        if ((unsigned)yy < 256u && (unsigned)xx < 256u)
            v = *(const i32x4*)(inb + (size_t)(yy * 256 + xx) * CPIN + slot * 8);
        *(i32x4*)&sm[((row * SPX + px) * SGRP + slot) * 4] = v;
    }
    if (tid < 64) sm[OUTOFF + tid * ODP + 15] = 0;
    __syncthreads();

    const int r = wv >> 1, xh = wv & 1;
    const short8* wp = (const short8*)wfrag;
    f32x4 acc[2][2];
#pragma unroll
    for (int mt = 0; mt < 2; ++mt)
#pragma unroll
        for (int c = 0; c < 2; ++c) acc[mt][c] = (f32x4){0.f,0.f,0.f,0.f};
#pragma unroll
    for (int tap = 0; tap < 9; ++tap) {
        const int dy = tap / 3 - 1, dx = tap % 3 - 1;
        const int rl = r + dy + 1;
        short8 af[2][KK];
#pragma unroll
        for (int mt = 0; mt < 2; ++mt)
#pragma unroll
            for (int kk = 0; kk < KK; ++kk)
                af[mt][kk] = wp[((tap * 2 + mt) * KK + kk) * 64 + lane];
        const int pl = 1 + xh * 16 + col + dx;
#pragma unroll
        for (int kk = 0; kk < KK; ++kk) {
            short8 bf = *(const short8*)&sm[((rl * SPX + pl) * SGRP + kk * 4 + g) * 4];
#pragma unroll
            for (int mt = 0; mt < 2; ++mt)
                acc[mt][kk] = __builtin_amdgcn_mfma_f32_16x16x32_bf16(af[mt][kk], bf, acc[mt][kk], 0, 0, 0);
        }
    }
    const float al = PRELU ? __ldg(alphap) : 0.f;
    const int px = xh * 16 + col;
#pragma unroll
    for (int mt = 0; mt < 2; ++mt) {
        const f32x4 a = acc[mt][0] + acc[mt][1];
#pragma unroll
        for (int e = 0; e < 2; ++e) {
            const int rb = mt * 16 + g * 4 + e * 2;
            if (rb < 30) {
                float v0 = a[e * 2]     + __ldg(bias + rb);
                float v1 = a[e * 2 + 1] + ((rb + 1 < 30) ? __ldg(bias + rb + 1) : 0.f);
                if (PRELU) { v0 = v0 >= 0.f ? v0 : al * v0; v1 = v1 >= 0.f ? v1 : al * v1; }
                if (rb + 1 >= 30) v1 = 0.f;
                sm[OUTOFF + (r * 32 + px) * ODP + (rb >> 1)] = pack2(v0, v1);
            }
        }
    }
    __syncthreads();

    for (int u = tid; u < 64 * CPP; u += 256) {
        const int slot = u & (CPP - 1), pxr = u / CPP;
        const int rr = pxr >> 5, opx = pxr & 31;
        i32x4 v = *(i32x4*)&sm[OUTOFF + pxr * ODP + slot * 4];
        const size_t go = ((size_t)b * HW + (size_t)(y0 + rr) * 256 + x0 + opx) * CPAD + slot * 8;
        *(i32x4*)(outb + go) = v;
    }
}

// ---------------------------------------------------------------------------
// Trident P: row-pair blocks (round-15 version, measured win).
// ---------------------------------------------------------------------------
template<int KK, int MR>
__global__ __launch_bounds__(384, (KK == 2 ? 5 : 8)) void trident_p(
    const unsigned short* __restrict__ in,
    const unsigned short* __restrict__ wf0, const unsigned short* __restrict__ wf1,
    const unsigned short* __restrict__ wf2,
    const float* __restrict__ b0, const float* __restrict__ b1, const float* __restrict__ b2,
    unsigned short* __restrict__ outb)
{
    constexpr int CPIN = KK * 32, CPAD = KK * 32;
    constexpr int SGR = KK * 4, SGRP = SGR + 1, SPX = 38, SROWS = 8;
    constexpr int MT_ = (KK == 2) ? 2 : 1;
    constexpr int CPP = KK * 4, ODP = (CPP + 1) * 4;
    constexpr int NSTGDW = SROWS * SPX * SGRP * 4;
    __shared__ __align__(16) unsigned int sm[NSTGDW];

    const int tid = threadIdx.x;
    const int lane = tid & 63, wv = tid >> 6;
    const int col = lane & 15, g = lane >> 4;
    const int bx = blockIdx.x;
    const int xcd = bx & 7, t = bx >> 3;
    const int y0 = xcd * 32 + (t & 15) * 2;
    const int x0 = ((t >> 4) & 7) * 32;
    const int b = blockIdx.z;
    const unsigned short* inb = in + (size_t)b * HW * CPIN;

    for (int u = tid; u < SROWS * SPX * SGR; u += 384) {
        const int slot = u & (SGR - 1);
        const int px = (u / SGR) % SPX;
        const int row = u / (SGR * SPX);
        const int yy = y0 + row - 3, xx = x0 - 3 + px;
        i32x4 v = {0,0,0,0};
        if ((unsigned)yy < 256u && (unsigned)xx < 256u)
            v = *(const i32x4*)(inb + (size_t)(yy * 256 + xx) * CPIN + slot * 8);
        *(i32x4*)&sm[((row * SPX + px) * SGRP + slot) * 4] = v;
    }
    __syncthreads();

    const int r = (wv >= 3) ? 1 : 0;
    const int dil = wv - r * 3, d = dil + 1;
    const unsigned short* wfx = (dil == 0) ? wf0 : ((dil == 1) ? wf1 : wf2);
    const float* bs = (dil == 0) ? b0 : ((dil == 1) ? b1 : b2);
    const short8* wp = (const short8*)wfx;

    f32x4 acc[MT_][2][2];
#pragma unroll
    for (int mt = 0; mt < MT_; ++mt)
#pragma unroll
        for (int nf = 0; nf < 2; ++nf)
#pragma unroll
            for (int c = 0; c < 2; ++c) acc[mt][nf][c] = (f32x4){0.f,0.f,0.f,0.f};

#pragma unroll
    for (int tap = 0; tap < 9; ++tap) {
        const int dy = tap / 3 - 1, dx = tap % 3 - 1;
        const int rl = 3 + r + dy * d;
        short8 af[MT_][KK];
#pragma unroll
        for (int mt = 0; mt < MT_; ++mt)
#pragma unroll
            for (int kk = 0; kk < KK; ++kk)
                af[mt][kk] = wp[((tap * MT_ + mt) * KK + kk) * 64 + lane];
#pragma unroll
        for (int nf = 0; nf < 2; ++nf) {
            const int pl = 3 + nf * 16 + col + dx * d;
#pragma unroll
            for (int kk = 0; kk < KK; ++kk) {
                const int c2 = (KK == 2) ? kk : (tap & 1);
                short8 bf = *(const short8*)&sm[((rl * SPX + pl) * SGRP + kk * 4 + g) * 4];
#pragma unroll
                for (int mt = 0; mt < MT_; ++mt)
                    acc[mt][nf][c2] = __builtin_amdgcn_mfma_f32_16x16x32_bf16(af[mt][kk], bf, acc[mt][nf][c2], 0, 0, 0);
            }
        }
    }
    __syncthreads();

#pragma unroll
    for (int nf = 0; nf < 2; ++nf) {
        const int px = nf * 16 + col;
        const int base = (r * 32 + px) * ODP;
#pragma unroll
        for (int mt = 0; mt < MT_; ++mt) {
            const f32x4 a = acc[mt][nf][0] + acc[mt][nf][1];
#pragma unroll
            for (int e = 0; e < 2; ++e) {
                const int rb = mt * 16 + g * 4 + e * 2;
                if (rb < MR) {
                    float v0 = a[e * 2] + __ldg(bs + rb);
                    float v1 = (rb + 1 < MR) ? a[e * 2 + 1] + __ldg(bs + rb + 1) : 0.f;
                    sm[base + ((dil * MR + rb) >> 1)] = pack2(v0, v1);
                }
            }
        }
    }
    {
        constexpr int NPAD = CPP * 4 - 3 * MR / 2;
        if (tid < 64 * NPAD) {
            const int pxr = tid / NPAD, dwp = 3 * MR / 2 + tid % NPAD;
            sm[pxr * ODP + dwp] = 0;
        }
    }
    __syncthreads();

    for (int u = tid; u < 64 * CPP; u += 384) {
        const int slot = u & (CPP - 1), pxr = u / CPP;
        const int rr = pxr >> 5, opx = pxr & 31;
        i32x4 v = *(i32x4*)&sm[pxr * ODP + slot * 4];
        const size_t go = ((size_t)b * HW + (size_t)(y0 + rr) * 256 + x0 + opx) * CPAD + slot * 8;
        *(i32x4*)(outb + go) = v;
    }
}

// ---------------------------------------------------------------------------
// AFLB2: KK=2 row-pair fused AFLB (round-16 version).
// ---------------------------------------------------------------------------
template<int RES>
__global__ __launch_bounds__(256, 5) void aflb2_k(
    const unsigned short* __restrict__ in,
    const unsigned short* __restrict__ awf, const float* __restrict__ ab,
    const unsigned short* __restrict__ fwf,
    const unsigned short* __restrict__ res,
    unsigned short* __restrict__ outb)
{
    constexpr int KK = 2, CPIN = 64, MTT = 4, CPAD = 64;
    constexpr int SROWS = 4, SPX = 34, SGR = 8, SGRP = 9;
    constexpr int CPP = 8, ODP = (CPP + 1) * 4;
    constexpr int NSTGDW = SROWS * SPX * SGRP * 4;
    constexpr int ATOFF = NSTGDW;
    __shared__ __align__(16) unsigned int sm[ATOFF + 2 * 32 * ODP];

    const int tid = threadIdx.x;
    const int lane = tid & 63, wv = tid >> 6;
    const int col = lane & 15, g = lane >> 4;
    const int bx = blockIdx.x;
    const int xcd = bx & 7, t = bx >> 3;
    const int y0 = xcd * 32 + (t & 15) * 2;
    const int x0 = ((t >> 4) & 7) * 32;
    const int b = blockIdx.z;
    const unsigned short* inb = in + (size_t)b * HW * CPIN;

    for (int u = tid; u < SROWS * SPX * SGR; u += 256) {
        const int slot = u & (SGR - 1);
        const int px = (u / SGR) % SPX;
        const int row = u / (SGR * SPX);
        const int yy = y0 + row - 1, xx = x0 - 1 + px;
        i32x4 v = {0,0,0,0};
        if ((unsigned)yy < 256u && (unsigned)xx < 256u)
            v = *(const i32x4*)(inb + (size_t)(yy * 256 + xx) * CPIN + slot * 8);
        *(i32x4*)&sm[((row * SPX + px) * SGRP + slot) * 4] = v;
    }
    __syncthreads();

    const short8* awp = (const short8*)awf;
    const short8* fwp = (const short8*)fwf;

    {
        const int r = wv >> 1, apx0 = (wv & 1) * 16;
        f32x4 aacc[2];
        aacc[0] = (f32x4){0.f,0.f,0.f,0.f}; aacc[1] = (f32x4){0.f,0.f,0.f,0.f};
#pragma unroll
        for (int tap = 0; tap < 9; ++tap) {
            const int dy = tap / 3 - 1, dx = tap % 3 - 1;
            const int rl = r + dy + 1;
            const int pl = 1 + apx0 + col + dx;
#pragma unroll
            for (int kk = 0; kk < KK; ++kk) {
                short8 afa = awp[(tap * KK + kk) * 64 + lane];
                short8 bf = *(const short8*)&sm[((rl * SPX + pl) * SGRP + kk * 4 + g) * 4];
                aacc[kk] = __builtin_amdgcn_mfma_f32_16x16x32_bf16(afa, bf, aacc[kk], 0, 0, 0);
            }
        }
        const f32x4 aa = aacc[0] + aacc[1];
        float v[4];
        float m = -1e30f;
#pragma unroll
        for (int rr = 0; rr < 4; ++rr) {
            const int row = g * 4 + rr;
            v[rr] = (row < 9) ? (aa[rr] + __ldg(ab + row)) : -1e30f;
            m = fmaxf(m, v[rr]);
        }
        m = fmaxf(m, __shfl_xor(m, 16));
        m = fmaxf(m, __shfl_xor(m, 32));
        float e[4]; float s = 0.f;
#pragma unroll
        for (int rr = 0; rr < 4; ++rr) { e[rr] = (g * 4 + rr < 9) ? __expf(v[rr] - m) : 0.f; s += e[rr]; }
        s += __shfl_xor(s, 16);
        s += __shfl_xor(s, 32);
        const float inv = 1.f / s;
        const int px = apx0 + col;
#pragma unroll
        for (int rr = 0; rr < 4; ++rr) {
            const int row = g * 4 + rr;
            if (row < 9) sm[ATOFF + (r * 32 + px) * 9 + row] = __float_as_uint(e[rr] * inv);
        }
    }
    __syncthreads();

    const int r = wv >> 1, mth = wv & 1;
    f32x4 acc[2][2];
#pragma unroll
    for (int mtl = 0; mtl < 2; ++mtl)
#pragma unroll
        for (int nf = 0; nf < 2; ++nf) acc[mtl][nf] = (f32x4){0.f,0.f,0.f,0.f};
#pragma unroll
    for (int tap = 0; tap < 9; ++tap) {
        const int dy = tap / 3 - 1, dx = tap % 3 - 1;
        const int rl = r + dy + 1;
        float av[2];
#pragma unroll
        for (int nf = 0; nf < 2; ++nf)
            av[nf] = __uint_as_float(sm[ATOFF + (r * 32 + nf * 16 + col) * 9 + tap]);
        short8 af[2][KK];
#pragma unroll
        for (int mtl = 0; mtl < 2; ++mtl)
#pragma unroll
            for (int kk = 0; kk < KK; ++kk)
                af[mtl][kk] = fwp[((tap * MTT + mth * 2 + mtl) * KK + kk) * 64 + lane];
#pragma unroll
        for (int nf = 0; nf < 2; ++nf) {
            const int pl = 1 + nf * 16 + col + dx;
            f32x4 p[2];
            p[0] = (f32x4){0.f,0.f,0.f,0.f}; p[1] = (f32x4){0.f,0.f,0.f,0.f};
#pragma unroll
            for (int kk = 0; kk < KK; ++kk) {
                short8 bf = *(const short8*)&sm[((rl * SPX + pl) * SGRP + kk * 4 + g) * 4];
#pragma unroll
                for (int mtl = 0; mtl < 2; ++mtl)
                    p[mtl] = __builtin_amdgcn_mfma_f32_16x16x32_bf16(af[mtl][kk], bf, p[mtl], 0, 0, 0);
            }
#pragma unroll
            for (int mtl = 0; mtl < 2; ++mtl)
#pragma unroll
                for (int rr = 0; rr < 4; ++rr)
                    acc[mtl][nf][rr] = fmaf(av[nf], p[mtl][rr], acc[mtl][nf][rr]);
        }
    }
    __syncthreads();

#pragma unroll
    for (int mtl = 0; mtl < 2; ++mtl) {
        const int mt = mth * 2 + mtl;
#pragma unroll
        for (int nf = 0; nf < 2; ++nf) {
            const int px = nf * 16 + col;
            const int base = ATOFF + (r * 32 + px) * ODP;
            const int rp = mt * 8 + g * 2;
            unsigned long long w =
                (unsigned long long)pack2(acc[mtl][nf][0], acc[mtl][nf][1]) |
                ((unsigned long long)pack2(acc[mtl][nf][2], acc[mtl][nf][3]) << 32);
            *(unsigned long long*)&sm[base + rp] = w;
        }
    }
    __syncthreads();

    for (int u = tid; u < 2 * 32 * CPP; u += 256) {
        const int slot = u & (CPP - 1), pxr = u / CPP;
        const int rr = pxr >> 5, opx = pxr & 31;
        i32x4 v = *(i32x4*)&sm[ATOFF + pxr * ODP + slot * 4];
        const size_t go = ((size_t)b * HW + (size_t)(y0 + rr) * 256 + x0 + opx) * CPAD + slot * 8;
        if (RES) v = addrelu4(v, *(const i32x4*)(res + go));
        *(i32x4*)(outb + go) = v;
    }
}

// ---------------------------------------------------------------------------
// Staged fused AFLB (KK=1, RPB=2 — 30ch path, round-11 version).
// ---------------------------------------------------------------------------
template<int KK, int RPB, int RES>
__global__ __launch_bounds__(256, 4) void aflb_p(
    const unsigned short* __restrict__ in,
    const unsigned short* __restrict__ awf, const float* __restrict__ ab,
    const unsigned short* __restrict__ fwf,
    const unsigned short* __restrict__ res,
    unsigned short* __restrict__ outb)
{
    constexpr int CPIN = KK * 32, MTT = 2 * KK, CPAD = 16 * MTT;
    constexpr int SROWS = RPB + 2, SPX = 66, SGR = KK * 4, SGRP = SGR + 1;
    constexpr int CPP = CPAD / 8, ODP = (CPP + 1) * 4;
    constexpr int NSTGDW = SROWS * SPX * SGRP * 4;
    constexpr int ATOFF = NSTGDW;
    constexpr int NATT = RPB * 64 * 9;
    constexpr int OUTOFF = ATOFF + NATT;
    __shared__ __align__(16) unsigned int sm[OUTOFF + RPB * 64 * ODP];

    const int tid = threadIdx.x;
    const int lane = tid & 63, wv = tid >> 6;
    const int col = lane & 15, g = lane >> 4;
    const int bx = blockIdx.x;
    const int xcd = bx & 7, t = bx >> 3;
    const int y0 = (RPB == 1) ? (xcd * 32 + (t & 31)) : (xcd * 32 + (t & 15) * 2);
    const int xseg = (RPB == 1) ? ((t >> 5) & 3) : ((t >> 4) & 3);
    const int x0 = xseg * 64;
    const int b = blockIdx.z;
    const unsigned short* inb = in + (size_t)b * HW * CPIN;

    for (int u = tid; u < SROWS * SPX * SGR; u += 256) {
        const int slot = u & (SGR - 1);
        const int px = (u / SGR) % SPX;
        const int row = u / (SGR * SPX);
        const int yy = y0 + row - 1, xx = x0 - 1 + px;
        i32x4 v = {0,0,0,0};
        if ((unsigned)yy < 256u && (unsigned)xx < 256u)
            v = *(const i32x4*)(inb + (size_t)(yy * 256 + xx) * CPIN + slot * 8);
        *(i32x4*)&sm[((row * SPX + px) * SGRP + slot) * 4] = v;
    }
    __syncthreads();

    const short8* awp = (const short8*)awf;
    const short8* fwp = (const short8*)fwf;

    constexpr int NF1 = (RPB == 1) ? 1 : 2;
    const int arow = (RPB == 1) ? 0 : (wv >> 1);
    const int apx0 = (RPB == 1) ? (wv * 16) : ((wv & 1) * 32);
    f32x4 aacc[NF1][2];
#pragma unroll
    for (int nf = 0; nf < NF1; ++nf)
#pragma unroll
        for (int c = 0; c < 2; ++c) aacc[nf][c] = (f32x4){0.f,0.f,0.f,0.f};
#pragma unroll
    for (int tap = 0; tap < 9; ++tap) {
        const int dy = tap / 3 - 1, dx = tap % 3 - 1;
        const int rl = arow + dy + 1;
        short8 afa[KK];
#pragma unroll
        for (int kk = 0; kk < KK; ++kk)
            afa[kk] = awp[(tap * KK + kk) * 64 + lane];
#pragma unroll
        for (int nf = 0; nf < NF1; ++nf) {
            const int pl = 1 + apx0 + nf * 16 + col + dx;
#pragma unroll
            for (int kk = 0; kk < KK; ++kk) {
                const int c2 = (KK == 2) ? kk : (tap & 1);
                short8 bf = *(const short8*)&sm[((rl * SPX + pl) * SGRP + kk * 4 + g) * 4];
                aacc[nf][c2] = __builtin_amdgcn_mfma_f32_16x16x32_bf16(afa[kk], bf, aacc[nf][c2], 0, 0, 0);
            }
        }
    }
#pragma unroll
    for (int nf = 0; nf < NF1; ++nf) {
        const f32x4 aa = aacc[nf][0] + aacc[nf][1];
        float v[4];
        float m = -1e30f;
#pragma unroll
        for (int r = 0; r < 4; ++r) {
            const int row = g * 4 + r;
            v[r] = (row < 9) ? (aa[r] + __ldg(ab + row)) : -1e30f;
            m = fmaxf(m, v[r]);
        }
        m = fmaxf(m, __shfl_xor(m, 16));
        m = fmaxf(m, __shfl_xor(m, 32));
        float e[4]; float s = 0.f;
#pragma unroll
        for (int r = 0; r < 4; ++r) { e[r] = (g * 4 + r < 9) ? __expf(v[r] - m) : 0.f; s += e[r]; }
        s += __shfl_xor(s, 16);
        s += __shfl_xor(s, 32);
        const float inv = 1.f / s;
        const int px = apx0 + nf * 16 + col;
#pragma unroll
        for (int r = 0; r < 4; ++r) {
            const int row = g * 4 + r;
            if (row < 9) sm[ATOFF + (arow * 64 + px) * 9 + row] = __float_as_uint(e[r] * inv);
        }
    }
    __syncthreads();

    const int prow = (RPB == 1) ? 0 : (wv >> 1);
    const int mth  = (RPB == 1) ? (wv >> 1) : 0;
    const int nfh  = wv & 1;
    f32x4 acc[2][2];
#pragma unroll
    for (int mtl = 0; mtl < 2; ++mtl)
#pragma unroll
        for (int nf = 0; nf < 2; ++nf) acc[mtl][nf] = (f32x4){0.f,0.f,0.f,0.f};
#pragma unroll
    for (int tap = 0; tap < 9; ++tap) {
        const int dy = tap / 3 - 1, dx = tap % 3 - 1;
        const int rl = prow + dy + 1;
        float av[2];
#pragma unroll
        for (int nf = 0; nf < 2; ++nf)
            av[nf] = __uint_as_float(sm[ATOFF + (prow * 64 + nfh * 32 + nf * 16 + col) * 9 + tap]);
        short8 af[2][KK];
#pragma unroll
        for (int mtl = 0; mtl < 2; ++mtl)
#pragma unroll
            for (int kk = 0; kk < KK; ++kk)
                af[mtl][kk] = fwp[((tap * MTT + (RPB == 1 ? mth * 2 + mtl : mtl)) * KK + kk) * 64 + lane];
#pragma unroll
        for (int nf = 0; nf < 2; ++nf) {
            const int pl = 1 + nfh * 32 + nf * 16 + col + dx;
            f32x4 p[2];
            p[0] = (f32x4){0.f,0.f,0.f,0.f}; p[1] = (f32x4){0.f,0.f,0.f,0.f};
#pragma unroll
            for (int kk = 0; kk < KK; ++kk) {
                short8 bf = *(const short8*)&sm[((rl * SPX + pl) * SGRP + kk * 4 + g) * 4];
#pragma unroll
                for (int mtl = 0; mtl < 2; ++mtl)
                    p[mtl] = __builtin_amdgcn_mfma_f32_16x16x32_bf16(af[mtl][kk], bf, p[mtl], 0, 0, 0);
            }
#pragma unroll
            for (int mtl = 0; mtl < 2; ++mtl)
#pragma unroll
                for (int r = 0; r < 4; ++r)
                    acc[mtl][nf][r] = fmaf(av[nf], p[mtl][r], acc[mtl][nf][r]);
        }
    }
    __syncthreads();

#pragma unroll
    for (int mtl = 0; mtl < 2; ++mtl) {
        const int mt = (RPB == 1) ? (mth * 2 + mtl) : mtl;
#pragma unroll
        for (int nf = 0; nf < 2; ++nf) {
            const int px = nfh * 32 + nf * 16 + col;
            const int base = OUTOFF + ((RPB == 2 ? prow * 64 : 0) + px) * ODP;
            const int rp = mt * 8 + g * 2;
            unsigned long long w =
                (unsigned long long)pack2(acc[mtl][nf][0], acc[mtl][nf][1]) |
                ((unsigned long long)pack2(acc[mtl][nf][2], acc[mtl][nf][3]) << 32);
            *(unsigned long long*)&sm[base + rp] = w;
        }
    }
    __syncthreads();

    constexpr int NOUT = RPB * 64 * CPP;
    for (int u = tid; u < NOUT; u += 256) {
        const int slot = u & (CPP - 1);
        const int px = (u / CPP) & 63;
        const int r = (RPB == 2) ? (u / (CPP * 64)) : 0;
        i32x4 v = *(i32x4*)&sm[OUTOFF + ((r * 64 + px) * ODP) + slot * 4];
        const size_t go = ((size_t)b * HW + (size_t)(y0 + r) * 256 + x0 + px) * CPAD + slot * 8;
        if (RES) v = addrelu4(v, *(const i32x4*)(res + go));
        *(i32x4*)(outb + go) = v;
    }
}

// ---------------------------------------------------------------------------
// Final conv 30->4 + ms_up, f32 NCHW output.
// ---------------------------------------------------------------------------
__global__ __launch_bounds__(256, 4) void final_k(
    const unsigned short* __restrict__ in,
    const unsigned short* __restrict__ wfrag,
    const float* __restrict__ bias,
    const float* __restrict__ msup, float* __restrict__ outf)
{
    constexpr int CPIN = 32, NF = 2;
    const int lane = threadIdx.x & 63, wv = threadIdx.x >> 6;
    const int col = lane & 15, g = lane >> 4;
    const int bx = blockIdx.x;
    const int xcd = bx & 7, t = bx >> 3;
    const int y = xcd * 32 + (t & 31);
    const int xh = t >> 5;
    const int b = blockIdx.z;
    const int x0 = xh * 128 + wv * 32;

    const unsigned short* inb = in + (size_t)b * HW * CPIN;
    const short8 kz = {0,0,0,0,0,0,0,0};
    const short8* wp = (const short8*)wfrag;

    f32x4 acc[NF];
#pragma unroll
    for (int nf = 0; nf < NF; ++nf) acc[nf] = (f32x4){0.f,0.f,0.f,0.f};
#pragma unroll
    for (int tap = 0; tap < 9; ++tap) {
        const int dy = tap / 3 - 1, dx = tap % 3 - 1;
        const int yy = y + dy;
        const bool yok = (unsigned)yy < 256u;
        const short8 af = wp[tap * 64 + lane];
#pragma unroll
        for (int nf = 0; nf < NF; ++nf) {
            const int xx = x0 + nf * 16 + col + dx;
            const bool ok = yok && ((unsigned)xx < 256u);
            const int pix = ok ? (yy * 256 + xx) : 0;
            short8 bf = *(const short8*)(inb + (size_t)pix * CPIN + g * 8);
            if (!ok) bf = kz;
            acc[nf] = __builtin_amdgcn_mfma_f32_16x16x32_bf16(af, bf, acc[nf], 0, 0, 0);
        }
    }
#pragma unroll
    for (int nf = 0; nf < NF; ++nf) {
        const int pix = y * 256 + x0 + nf * 16 + col;
        if (g == 0) {
#pragma unroll
            for (int r = 0; r < 4; ++r) {
                const size_t oi = ((size_t)b * 4 + r) * HW + pix;
                outf[oi] = acc[nf][r] + __ldg(bias + r) + msup[oi];
            }
        }
    }
}

// ---------------------------------------------------------------------------
// Weight prep (parallel, shift-based indexing).
// ---------------------------------------------------------------------------
struct PrepDesc { const float* src; int cout, cin, kksh, mtsh, flags, dstoff, n; };
struct PrepArgs { PrepDesc d[18]; };

__global__ __launch_bounds__(256) void prep_k(PrepArgs pa, unsigned short* __restrict__ wb)
{
    const PrepDesc d = pa.d[blockIdx.y];
    const int e = blockIdx.x * 256 + threadIdx.x;
    if (e >= d.n) return;
    const int j = e & 7;
    const int lane = (e >> 3) & 63;
    const int i512 = e >> 9;
    const int kk = i512 & ((1 << d.kksh) - 1);
    const int mt = (i512 >> d.kksh) & ((1 << d.mtsh) - 1);
    const int tap = i512 >> (d.kksh + d.mtsh);
    const int rpos = mt * 16 + (lane & 15);
    const int kpos = kk * 32 + (lane >> 4) * 8 + j;
    int o = rpos, ic = kpos;
    bool ok = true;
    if (d.flags & 2) {
        if (rpos < 30) o = rpos;
        else if (rpos >= 32 && rpos < 62) o = rpos - 2;
        else ok = false;
    }
    if (d.flags & 1) {
        if (kpos < 30) ic = kpos;
        else if (kpos >= 32 && kpos < 62) ic = kpos - 2;
        else ok = false;
    }
    float v = 0.f;
    if (ok && o < d.cout && ic < d.cin) v = d.src[(o * d.cin + ic) * 9 + tap];
    wb[d.dstoff + e] = f2bf(v);
}

// ---------------------------------------------------------------------------
// up-conv (ms_org 4->64 @64x64, f32 NCHW) — small, VALU direct conv.
// ---------------------------------------------------------------------------
template<int CIN, int COUT, int OCB, int H, int W>
__launch_bounds__(256)
__global__ void upconv_k(const float* __restrict__ in, const float* __restrict__ wgt,
                         const float* __restrict__ bias, float* __restrict__ out)
{
    constexpr int HWp = H * W;
    constexpr int NOCB = COUT / OCB;
    const int tx = threadIdx.x;
    const int lx = tx & 63, ly = tx >> 6;
    const int gx = blockIdx.x * 64 + lx;
    const int gy = blockIdx.y * 4 + ly;
    const int b = blockIdx.z / NOCB;
    const int ocb = blockIdx.z % NOCB;
    const int pixp = gy * W + gx;
    const float* inb = in + (size_t)b * CIN * HWp;

    int off[9]; float mul[9];
#pragma unroll
    for (int dy = 0; dy < 3; ++dy)
#pragma unroll
        for (int dx = 0; dx < 3; ++dx) {
            int p = dy * 3 + dx;
            int yy = gy + dy - 1, xx = gx + dx - 1;
            bool okp = ((unsigned)yy < (unsigned)H) && ((unsigned)xx < (unsigned)W);
            off[p] = okp ? (yy * W + xx) : 0;
            mul[p] = okp ? 1.f : 0.f;
        }
    float acc[OCB];
#pragma unroll
    for (int o = 0; o < OCB; ++o) acc[o] = 0.f;
    const float* wbase = wgt + (size_t)(ocb * OCB) * CIN * 9;
#pragma unroll
    for (int ic = 0; ic < CIN; ++ic) {
        const float* ip = inb + (size_t)ic * HWp;
        float tv[9];
#pragma unroll
        for (int p = 0; p < 9; ++p) tv[p] = __ldg(ip + off[p]) * mul[p];
#pragma unroll
        for (int o = 0; o < OCB; ++o) {
            const float* wq = wbase + (size_t)(o * CIN + ic) * 9;
#pragma unroll
            for (int p = 0; p < 9; ++p) acc[o] = fmaf(tv[p], wq[p], acc[o]);
        }
    }
#pragma unroll
    for (int o = 0; o < OCB; ++o)
        out[((size_t)b * COUT + ocb * OCB + o) * HWp + pixp] = acc[o] + __ldg(bias + ocb * OCB + o);
}

// ---------------------------------------------------------------------------
// Build data1 (prelu(pixshuf(t_up))||pan) and ms_up as NHWC bf16 pad32.
// ---------------------------------------------------------------------------
__global__ __launch_bounds__(256) void build_inputs(
    const float* __restrict__ tup, const float* __restrict__ pan,
    const float* __restrict__ aup, const float* __restrict__ msup,
    unsigned short* __restrict__ data1, unsigned short* __restrict__ msb)
{
    const int i = blockIdx.x * 256 + threadIdx.x;
    const int b = i >> 16, pixp = i & 65535;
    const int y = pixp >> 8, x = pixp & 255;
    unsigned short o[32];
#pragma unroll
    for (int c = 0; c < 32; ++c) o[c] = 0;
    unsigned short* dst;
    if (blockIdx.y == 0) {
        const float a = __ldg(aup);
#pragma unroll
        for (int c = 0; c < 4; ++c) {
            const int ch = c * 16 + (y & 3) * 4 + (x & 3);
            float v = tup[(((size_t)b * 64 + ch) << 12) + ((y >> 2) << 6) + (x >> 2)];
            v = (v >= 0.f) ? v : a * v;
            o[c] = f2bf(v);
        }
        o[4] = f2bf(pan[((size_t)b << 16) + pixp]);
        dst = data1;
    } else {
#pragma unroll
        for (int c = 0; c < 4; ++c)
            o[c] = f2bf(msup[(((size_t)b * 4 + c) << 16) + pixp]);
        dst = msb;
    }
    short8* dp = (short8*)(dst + (size_t)i * 32);
#pragma unroll
    for (int q = 0; q < 4; ++q) {
        short8 s;
#pragma unroll
        for (int r = 0; r < 8; ++r) s[r] = (short)o[q * 8 + r];
        dp[q] = s;
    }
}

// ---------------------------------------------------------------------------
extern "C" void kernel_launch(void* const* d_in, const int* in_sizes, int n_in,
                              void* d_out, int out_size, void* d_ws, size_t ws_size,
                              hipStream_t stream) {
    const float* ms_up  = (const float*)d_in[0];
    const float* ms_org = (const float*)d_in[1];
    const float* pan    = (const float*)d_in[2];
    const float* w_up4  = (const float*)d_in[3];
    const float* b_up4  = (const float*)d_in[4];
    const float* a_up4  = (const float*)d_in[5];
    const float* w_blk53= (const float*)d_in[6];
    const float* b_blk53= (const float*)d_in[7];
    const float* a_blk53= (const float*)d_in[8];
    const float* w_blk43= (const float*)d_in[9];
    const float* b_blk43= (const float*)d_in[10];
    const float* a_blk43= (const float*)d_in[11];
    const float* w1a=(const float*)d_in[12]; const float* b1a=(const float*)d_in[13];
    const float* w1b=(const float*)d_in[14]; const float* b1b=(const float*)d_in[15];
    const float* w1c=(const float*)d_in[16]; const float* b1c=(const float*)d_in[17];
    const float* aw1=(const float*)d_in[18]; const float* ab1=(const float*)d_in[19];
    const float* fw1=(const float*)d_in[20];
    const float* aw2=(const float*)d_in[21]; const float* ab2=(const float*)d_in[22];
    const float* fw2=(const float*)d_in[23];
    const float* w_blk2=(const float*)d_in[24]; const float* b_blk2=(const float*)d_in[25]; const float* a_blk2=(const float*)d_in[26];
    const float* w2a=(const float*)d_in[27]; const float* b2a=(const float*)d_in[28];
    const float* w2b=(const float*)d_in[29]; const float* b2b=(const float*)d_in[30];
    const float* w2c=(const float*)d_in[31]; const float* b2c=(const float*)d_in[32];
    const float* aw3=(const float*)d_in[33]; const float* ab3=(const float*)d_in[34];
    const float* fw3=(const float*)d_in[35];
    const float* aw4=(const float*)d_in[36]; const float* ab4=(const float*)d_in[37];
    const float* fw4=(const float*)d_in[38];
    const float* w_c6=(const float*)d_in[39]; const float* b_c6=(const float*)d_in[40];

    float* out = (float*)d_out;
    char* ws = (char*)d_ws;

    const size_t BIG = (size_t)2 * HW * 64 * 2;   // 16.78 MB (NHWC pad64 bf16)
    const size_t HALF = BIG / 2;
    unsigned short* bufA = (unsigned short*)(ws);
    unsigned short* bufB = (unsigned short*)(ws + BIG);
    unsigned short* bufC = (unsigned short*)(ws + 2 * BIG);
    unsigned short* data1 = bufC;
    float*          t_up  = (float*)(ws + 2 * BIG + HALF);
    unsigned short* msb   = bufB;
    unsigned short* bufD = bufC;
    unsigned short* bufE = bufB;
    unsigned short* bufF = bufA;
    unsigned short* wb = (unsigned short*)(ws + 3 * BIG);

    if (ws_size < 3 * BIG + 1000000) return;

    PrepArgs pa;
    int off = 0, li = 0;
    auto add = [&](const float* s, int cout, int cin, int mtsh, int kksh, int flags) {
        const int n = 9 << (mtsh + kksh + 9);
        pa.d[li].src = s; pa.d[li].cout = cout; pa.d[li].cin = cin;
        pa.d[li].kksh = kksh; pa.d[li].mtsh = mtsh; pa.d[li].flags = flags;
        pa.d[li].dstoff = off; pa.d[li].n = n;
        int ret = off; off += n; ++li; return ret;
    };
    const int o_blk43 = add(w_blk43, 30, 4, 1, 0, 0);
    const int o_blk53 = add(w_blk53, 30, 5, 1, 0, 0);
    const int o_w1a   = add(w1a, 20, 60, 1, 1, 1);
    const int o_w1b   = add(w1b, 20, 60, 1, 1, 1);
    const int o_w1c   = add(w1c, 20, 60, 1, 1, 1);
    const int o_aw1   = add(aw1,  9, 60, 0, 1, 0);
    const int o_fw1   = add(fw1, 60, 60, 2, 1, 0);
    const int o_aw2   = add(aw2,  9, 60, 0, 1, 0);
    const int o_fw2   = add(fw2, 60, 60, 2, 1, 2);
    const int o_blk2  = add(w_blk2, 30, 60, 1, 1, 1);
    const int o_w2a   = add(w2a, 10, 30, 0, 0, 0);
    const int o_w2b   = add(w2b, 10, 30, 0, 0, 0);
    const int o_w2c   = add(w2c, 10, 30, 0, 0, 0);
    const int o_aw3   = add(aw3,  9, 30, 0, 0, 0);
    const int o_fw3   = add(fw3, 30, 30, 1, 0, 0);
    const int o_aw4   = add(aw4,  9, 30, 0, 0, 0);
    const int o_fw4   = add(fw4, 30, 30, 1, 0, 0);
    const int o_c6    = add(w_c6,  4, 30, 0, 0, 0);

    prep_k<<<dim3(144, 18), 256, 0, stream>>>(pa, wb);

    upconv_k<4, 64, 16, 64, 64><<<dim3(1, 16, 8), 256, 0, stream>>>(ms_org, w_up4, b_up4, t_up);
    build_inputs<<<dim3(512, 2), 256, 0, stream>>>(t_up, pan, a_up4, ms_up, data1, msb);

    const dim3 B256(256), B384(384);
    const dim3 G2(1024, 1, 4);   // merged dual sconv
    const dim3 GP(1024, 1, 2);   // row-pair blocks
    const dim3 GH(512, 1, 2);    // RPB=2 staged / final

    // out1 (bufA, pad64, split-60): blk43 -> rows 0..29, blk53 -> rows 32..61
    sconv2_k<1><<<G2,B256,0,stream>>>(msb, wb+o_blk43, b_blk43, a_blk43, 0,
                                      data1, wb+o_blk53, b_blk53, a_blk53, 32,
                                      bufA, 64);

    // ---- rmrs1 (60 ch) ----
    trident_p<2,20><<<GP,B384,0,stream>>>(bufA, wb+o_w1a, wb+o_w1b, wb+o_w1c, b1a, b1b, b1c, bufB);
    aflb2_k<0><<<GP,B256,0,stream>>>(bufB, wb+o_aw1, ab1, wb+o_fw1, nullptr, bufC);
    aflb2_k<1><<<GP,B256,0,stream>>>(bufC, wb+o_aw2, ab2, wb+o_fw2, bufA,   bufB);

    // blk2: out2 -> 30ch (bufD pad32), row-pair staged
    sconvp_k<1><<<GP,B256,0,stream>>>(bufB, wb+o_blk2, b_blk2, a_blk2, bufD);

    // ---- rmrs2 (30 ch) ----
    trident_p<1,10><<<GP,B384,0,stream>>>(bufD, wb+o_w2a, wb+o_w2b, wb+o_w2c, b2a, b2b, b2c, bufE);
    aflb_p<1,2,0><<<GH,B256,0,stream>>>(bufE, wb+o_aw3, ab3, wb+o_fw3, nullptr, bufF);
    aflb_p<1,2,1><<<GH,B256,0,stream>>>(bufF, wb+o_aw4, ab4, wb+o_fw4, bufD,   bufE);

    // final: conv 30->4 + ms_up (f32 NCHW out)
    final_k<<<GH,B256,0,stream>>>(bufE, wb+o_c6, b_c6, ms_up, out);
}